// Round 5
// baseline (280.289 us; speedup 1.0000x reference)
//
#include <hip/hip_runtime.h>
#include <math.h>

typedef unsigned short ushort_t;
typedef __bf16 bf16x8 __attribute__((ext_vector_type(8)));
typedef float f32x4 __attribute__((ext_vector_type(4)));

// ---------------------------------------------------------------------------
// fp32 <-> bf16 helpers
// ---------------------------------------------------------------------------
__device__ __forceinline__ ushort_t f2b_rne(float f) {
    union { float f; unsigned int u; } c;
    c.f = f;
    unsigned int u = c.u;
    u += 0x7FFFu + ((u >> 16) & 1u);
    return (ushort_t)(u >> 16);
}
__device__ __forceinline__ float b2f(ushort_t v) {
    union { unsigned int u; float f; } c;
    c.u = ((unsigned int)v) << 16;
    return c.f;
}

__global__ void f2b_flat(const float* __restrict__ in, ushort_t* __restrict__ out, int n4) {
    int i = blockIdx.x * blockDim.x + threadIdx.x;
    if (i >= n4) return;
    float4 v = ((const float4*)in)[i];
    ushort_t o[4] = {f2b_rne(v.x), f2b_rne(v.y), f2b_rne(v.z), f2b_rne(v.w)};
    *(uint2*)&out[(size_t)i * 4] = *(uint2*)o;
}

// fp32 [R,C] -> bf16 [C,R] (transpose + convert)
__global__ void f2b_t(const float* __restrict__ in, ushort_t* __restrict__ out,
                      int R, int C) {
    __shared__ float t[32][33];
    const int tx = threadIdx.x, ty = threadIdx.y;
    const int r0 = blockIdx.y * 32, c0 = blockIdx.x * 32;
#pragma unroll
    for (int i = 0; i < 4; i++)
        t[ty + 8 * i][tx] = in[(size_t)(r0 + ty + 8 * i) * C + c0 + tx];
    __syncthreads();
#pragma unroll
    for (int i = 0; i < 4; i++)
        out[(size_t)(c0 + ty + 8 * i) * R + r0 + tx] = f2b_rne(t[tx][ty + 8 * i]);
}

// ---------------------------------------------------------------------------
// bf16 MFMA GEMM: C[M,N] = A[M,K] @ Bt[N,K]^T. 128x128 tile, 4 waves, BK=32.
// ---------------------------------------------------------------------------
template <bool BF16OUT>
__global__ __launch_bounds__(256) void gemm_bt(const ushort_t* __restrict__ A,
                                               const ushort_t* __restrict__ Bt,
                                               void* __restrict__ Cout,
                                               int M, int N, int K) {
    __shared__ ushort_t As[128 * 40];  // stride 40 elem = 5x16B granules
    __shared__ ushort_t Bs[128 * 40];

    const int t = threadIdx.x;
    const int lane = t & 63;
    const int wave = t >> 6;
    const int quad = lane >> 4;
    const int l15 = lane & 15;
    const int wm = (wave >> 1) * 64;
    const int wn = (wave & 1) * 64;
    const int row0 = blockIdx.y * 128, col0 = blockIdx.x * 128;

    const int srow = t >> 2;
    const int sseg = t & 3;
    const ushort_t* ga0 = A + (size_t)(row0 + srow) * K + sseg * 8;
    const ushort_t* ga1 = A + (size_t)(row0 + srow + 64) * K + sseg * 8;
    const ushort_t* gb0 = Bt + (size_t)(col0 + srow) * K + sseg * 8;
    const ushort_t* gb1 = Bt + (size_t)(col0 + srow + 64) * K + sseg * 8;

    f32x4 acc[4][4] = {};

    bf16x8 ra0 = *(const bf16x8*)ga0;
    bf16x8 ra1 = *(const bf16x8*)ga1;
    bf16x8 rb0 = *(const bf16x8*)gb0;
    bf16x8 rb1 = *(const bf16x8*)gb1;

    for (int k0 = 0; k0 < K; k0 += 32) {
        __syncthreads();
        *(bf16x8*)&As[srow * 40 + sseg * 8] = ra0;
        *(bf16x8*)&As[(srow + 64) * 40 + sseg * 8] = ra1;
        *(bf16x8*)&Bs[srow * 40 + sseg * 8] = rb0;
        *(bf16x8*)&Bs[(srow + 64) * 40 + sseg * 8] = rb1;
        __syncthreads();
        if (k0 + 32 < K) {
            ra0 = *(const bf16x8*)(ga0 + k0 + 32);
            ra1 = *(const bf16x8*)(ga1 + k0 + 32);
            rb0 = *(const bf16x8*)(gb0 + k0 + 32);
            rb1 = *(const bf16x8*)(gb1 + k0 + 32);
        }
        bf16x8 af[4], bfr[4];
#pragma unroll
        for (int i = 0; i < 4; i++)
            af[i] = *(const bf16x8*)&As[(wm + i * 16 + l15) * 40 + quad * 8];
#pragma unroll
        for (int j = 0; j < 4; j++)
            bfr[j] = *(const bf16x8*)&Bs[(wn + j * 16 + l15) * 40 + quad * 8];
#pragma unroll
        for (int i = 0; i < 4; i++)
#pragma unroll
            for (int j = 0; j < 4; j++)
                acc[i][j] = __builtin_amdgcn_mfma_f32_16x16x32_bf16(
                    af[i], bfr[j], acc[i][j], 0, 0, 0);
    }

#pragma unroll
    for (int i = 0; i < 4; i++)
#pragma unroll
        for (int j = 0; j < 4; j++)
#pragma unroll
            for (int r = 0; r < 4; r++) {
                const int row = row0 + wm + i * 16 + quad * 4 + r;
                const int col = col0 + wn + j * 16 + l15;
                if (BF16OUT)
                    ((ushort_t*)Cout)[(size_t)row * N + col] = f2b_rne(acc[i][j][r]);
                else
                    ((float*)Cout)[(size_t)row * N + col] = acc[i][j][r];
            }
}

// ---------------------------------------------------------------------------
// Scores via MFMA: S[b,h,64,n] = (Q_h @ K_h^T) / sqrt(96), bf16 in, fp32 out.
// ---------------------------------------------------------------------------
__global__ __launch_bounds__(256) void scores_mfma(const ushort_t* __restrict__ qb,
                                                   const ushort_t* __restrict__ kb,
                                                   float* __restrict__ S, int n) {
    const int bh = blockIdx.y;
    const int b = bh >> 3, h = bh & 7;
    const int n0 = blockIdx.x * 128;
    const int t = threadIdx.x;
    const int lane = t & 63, wave = t >> 6;
    const int quad = lane >> 4, l15 = lane & 15;
    const int wm = (wave >> 1) * 32;
    const int wn = (wave & 1) * 64;

    __shared__ ushort_t Qs[64 * 104];
    __shared__ ushort_t Ks[128 * 104];

    for (int g = t; g < 768; g += 256) {
        const int r = g / 12, s = g - r * 12;
        *(bf16x8*)&Qs[r * 104 + s * 8] =
            *(const bf16x8*)&qb[(size_t)(b * 64 + r) * 768 + h * 96 + s * 8];
    }
    for (int g = t; g < 1536; g += 256) {
        const int r = g / 12, s = g - r * 12;
        *(bf16x8*)&Ks[r * 104 + s * 8] =
            *(const bf16x8*)&kb[(size_t)(b * n + n0 + r) * 768 + h * 96 + s * 8];
    }
    __syncthreads();

    f32x4 acc[2][4] = {};
#pragma unroll
    for (int ks = 0; ks < 3; ks++) {
        bf16x8 af[2], bfr[4];
#pragma unroll
        for (int i = 0; i < 2; i++)
            af[i] = *(const bf16x8*)&Qs[(wm + i * 16 + l15) * 104 + ks * 32 + quad * 8];
#pragma unroll
        for (int j = 0; j < 4; j++)
            bfr[j] = *(const bf16x8*)&Ks[(wn + j * 16 + l15) * 104 + ks * 32 + quad * 8];
#pragma unroll
        for (int i = 0; i < 2; i++)
#pragma unroll
            for (int j = 0; j < 4; j++)
                acc[i][j] = __builtin_amdgcn_mfma_f32_16x16x32_bf16(
                    af[i], bfr[j], acc[i][j], 0, 0, 0);
    }

    const float sc = 0.10206207261596575f;  // 1/sqrt(96)
    float* Sp = S + (size_t)bh * 64 * n;
#pragma unroll
    for (int i = 0; i < 2; i++)
#pragma unroll
        for (int j = 0; j < 4; j++)
#pragma unroll
            for (int r = 0; r < 4; r++) {
                const int row = wm + i * 16 + quad * 4 + r;
                const int col = n0 + wn + j * 16 + l15;
                Sp[(size_t)row * n + col] = acc[i][j][r] * sc;
            }
}

// ---------------------------------------------------------------------------
// Per-row softmax stats over S rows: mstat=max, lstat=sum(exp(s-max)).
// ---------------------------------------------------------------------------
__global__ void rowstat(const float* __restrict__ S, float* __restrict__ mstat,
                        float* __restrict__ lstat, int n) {
    const int row = blockIdx.x;
    const int tid = threadIdx.x;
    const float4* p = (const float4*)(S + (size_t)row * n);
    const int n4 = n >> 2;

    float m = -1e30f;
    for (int i = tid; i < n4; i += 256) {
        float4 v = p[i];
        m = fmaxf(m, fmaxf(fmaxf(v.x, v.y), fmaxf(v.z, v.w)));
    }
    __shared__ float red[256];
    red[tid] = m;
    __syncthreads();
    for (int off = 128; off > 0; off >>= 1) {
        if (tid < off) red[tid] = fmaxf(red[tid], red[tid + off]);
        __syncthreads();
    }
    const float mx = red[0];
    __syncthreads();

    float s = 0.f;
    for (int i = tid; i < n4; i += 256) {
        float4 v = p[i];
        s += expf(v.x - mx) + expf(v.y - mx) + expf(v.z - mx) + expf(v.w - mx);
    }
    red[tid] = s;
    __syncthreads();
    for (int off = 128; off > 0; off >>= 1) {
        if (tid < off) red[tid] += red[tid + off];
        __syncthreads();
    }
    if (tid == 0) { mstat[row] = mx; lstat[row] = red[0]; }
}

// ---------------------------------------------------------------------------
// Per-row LN stats of bf16 h1 (4096-wide): mu and rstd. One block per row.
// ---------------------------------------------------------------------------
__global__ void rowstat_h1(const ushort_t* __restrict__ h1b,
                           float* __restrict__ mu, float* __restrict__ rstd) {
    const int row = blockIdx.x;
    const int tid = threadIdx.x;
    const ushort_t* p = h1b + (size_t)row * 4096;

    float v[16];
#pragma unroll
    for (int g = 0; g < 2; g++) {
        bf16x8 x = *(const bf16x8*)&p[(tid + g * 256) * 8];
#pragma unroll
        for (int j = 0; j < 8; j++) v[g * 8 + j] = (float)x[j];
    }
    float s = 0.f;
#pragma unroll
    for (int i = 0; i < 16; i++) s += v[i];

    __shared__ float red[256];
    red[tid] = s;
    __syncthreads();
    for (int off = 128; off > 0; off >>= 1) {
        if (tid < off) red[tid] += red[tid + off];
        __syncthreads();
    }
    const float m = red[0] * (1.0f / 4096.0f);
    __syncthreads();

    float s2 = 0.f;
#pragma unroll
    for (int i = 0; i < 16; i++) { const float d = v[i] - m; s2 += d * d; }
    red[tid] = s2;
    __syncthreads();
    for (int off = 128; off > 0; off >>= 1) {
        if (tid < off) red[tid] += red[tid + off];
        __syncthreads();
    }
    if (tid == 0) {
        mu[row] = m;
        rstd[row] = rsqrtf(red[0] * (1.0f / 4096.0f) + 1e-5f);
    }
}

// ---------------------------------------------------------------------------
// A[b,qi,h,r] = g_c*( sum_n w_n*h1raw[n,c] - sum_n w_n*mu_n ) + b_c,
//   w_n = exp(S-m)/l * rstd_n,  c = qi*64+r.   (LayerNorm folded in.)
// One block (256 thr) per (b,qi). Each h1 element read ONCE; w broadcast
// from LDS as float4; 8 accumulators/thread; cross-chunk LDS reduce.
// ---------------------------------------------------------------------------
__global__ __launch_bounds__(256) void attn_vmid_ln(
    const float* __restrict__ S, const float* __restrict__ mstat,
    const float* __restrict__ lstat, const float* __restrict__ mu,
    const float* __restrict__ rstd, const ushort_t* __restrict__ h1b,
    const float* __restrict__ ln_g, const float* __restrict__ ln_b,
    float* __restrict__ Abuf, int n) {
    const int b = blockIdx.x >> 6;
    const int qi = blockIdx.x & 63;
    const int tid = threadIdx.x;

    extern __shared__ float smem[];
    float* sw   = smem;            // [8*n]  w values
    float* saux = smem + 8 * n;    // [2*n]  mu | rstd, later reduce buffer
    float* smu  = saux;
    float* srs  = saux + n;
    __shared__ float sm[8], sl[8], swmu[8];

    if (tid < 8) {
        sm[tid] = mstat[((size_t)b * 8 + tid) * 64 + qi];
        sl[tid] = lstat[((size_t)b * 8 + tid) * 64 + qi];
    }
    for (int i = tid; i < n; i += 256) {
        smu[i] = mu[(size_t)b * n + i];
        srs[i] = rstd[(size_t)b * n + i];
    }
    __syncthreads();

    // stage w[h][ni] = exp(S-m)/l * rstd
    for (int i = tid; i < 8 * n; i += 256) {
        const int hh = i / n;
        const int ni = i - hh * n;
        const float e = expf(S[(((size_t)(b * 8 + hh) * 64 + qi)) * n + ni] - sm[hh]);
        sw[hh * n + ni] = e / sl[hh] * srs[ni];
    }
    __syncthreads();

    // wmu[h] = sum_n w[h][n]*mu[n] : 4 waves, 2 h-rows each
    {
        const int wave = tid >> 6, lane = tid & 63;
#pragma unroll
        for (int s = 0; s < 2; s++) {
            const int h = wave * 2 + s;
            float acc = 0.f;
            for (int ni = lane; ni < n; ni += 64) acc += sw[h * n + ni] * smu[ni];
#pragma unroll
            for (int off = 32; off > 0; off >>= 1) acc += __shfl_down(acc, off);
            if (lane == 0) swmu[h] = acc;
        }
    }
    __syncthreads();

    // main: thread (r = tid&63, cgrp = tid>>6) streams n/4 rows of h1
    const int r = tid & 63;
    const int cgrp = tid >> 6;
    const int nchunk = n >> 2;
    const int base = cgrp * nchunk;
    const ushort_t* vp = h1b + ((size_t)b * n + base) * 4096 + qi * 64 + r;

    float acc[8] = {};
    for (int o = 0; o < nchunk; o += 4) {
        float v0 = b2f(vp[(size_t)(o + 0) * 4096]);
        float v1 = b2f(vp[(size_t)(o + 1) * 4096]);
        float v2 = b2f(vp[(size_t)(o + 2) * 4096]);
        float v3 = b2f(vp[(size_t)(o + 3) * 4096]);
#pragma unroll
        for (int h = 0; h < 8; h++) {
            const float4 w4 = *(const float4*)&sw[h * n + base + o];
            acc[h] += w4.x * v0 + w4.y * v1 + w4.z * v2 + w4.w * v3;
        }
    }
    __syncthreads();
    // partial reduce across cgrp via saux (mu/rstd dead now): [cgrp][h*64+r]
#pragma unroll
    for (int h = 0; h < 8; h++) saux[cgrp * 512 + h * 64 + r] = acc[h];
    __syncthreads();

#pragma unroll
    for (int s = 0; s < 2; s++) {
        const int o = tid + s * 256;         // output index 0..511
        const int h = o >> 6;
        const int rr = o & 63;
        const float v = saux[o] + saux[512 + o] + saux[1024 + o] + saux[1536 + o];
        const int c = qi * 64 + rr;
        Abuf[(size_t)blockIdx.x * 512 + o] = ln_g[c] * (v - swmu[h]) + ln_b[c];
    }
}

// ---------------------------------------------------------------------------
// out_pre[b,qi,d] = sum_r A[b,qi,h(d)*64+r] * Wc[qi,r,d]  (bf16 output)
// ---------------------------------------------------------------------------
__global__ void apply_wc(const float* __restrict__ Abuf,
                         const float* __restrict__ Wc,
                         ushort_t* __restrict__ out_pre) {
    const int qi = blockIdx.x & 63;
    const int d = threadIdx.x;

    __shared__ float sA[512];
    if (d < 512) sA[d] = Abuf[(size_t)blockIdx.x * 512 + d];
    __syncthreads();

    const int h = d / 96;
    const float* wp = Wc + (size_t)qi * 64 * 768 + d;
    float acc = 0.f;
#pragma unroll
    for (int r = 0; r < 64; r++) acc += sA[h * 64 + r] * wp[(size_t)r * 768];

    out_pre[(size_t)blockIdx.x * 768 + d] = f2b_rne(acc);
}

// ---------------------------------------------------------------------------
extern "C" void kernel_launch(void* const* d_in, const int* in_sizes, int n_in,
                              void* d_out, int out_size, void* d_ws, size_t ws_size,
                              hipStream_t stream) {
    const float* x       = (const float*)d_in[0];
    const float* context = (const float*)d_in[1];
    const float* Wq      = (const float*)d_in[2];
    const float* Wk      = (const float*)d_in[3];
    const float* Wv1     = (const float*)d_in[4];
    const float* ln_g    = (const float*)d_in[5];
    const float* ln_b    = (const float*)d_in[6];
    const float* Wc      = (const float*)d_in[7];
    const float* Wout    = (const float*)d_in[8];
    float* out = (float*)d_out;

    const int b = in_sizes[0] / (64 * 768);
    const int n = in_sizes[1] / (b * 768);
    const int M  = b * 64;    // 256
    const int Mn = b * n;     // 4096

    float* ws = (float*)d_ws;
    size_t off = 0;
    float* S     = ws + off;  off += (size_t)b * 8 * 64 * n;
    float* Abuf  = ws + off;  off += (size_t)M * 512;
    float* mstat = ws + off;  off += (size_t)b * 8 * 64;
    float* lstat = ws + off;  off += (size_t)b * 8 * 64;
    float* muh   = ws + off;  off += (size_t)Mn;
    float* rstdh = ws + off;  off += (size_t)Mn;

    ushort_t* us = (ushort_t*)(ws + off);
    size_t uo = 0;
    ushort_t* x_b    = us + uo;  uo += (size_t)M * 768;
    ushort_t* ctx_b  = us + uo;  uo += (size_t)Mn * 768;
    ushort_t* qb     = us + uo;  uo += (size_t)M * 768;
    ushort_t* kb     = us + uo;  uo += (size_t)Mn * 768;
    ushort_t* h1b    = us + uo;  uo += (size_t)Mn * 4096;
    ushort_t* Wq_t   = us + uo;  uo += (size_t)768 * 768;
    ushort_t* Wk_t   = us + uo;  uo += (size_t)768 * 768;
    ushort_t* Wv1_t  = us + uo;  uo += (size_t)4096 * 768;
    ushort_t* Wout_t = us + uo;  uo += (size_t)768 * 768;
    ushort_t* outp_b = us + uo;  uo += (size_t)M * 768;

    const dim3 tblk(32, 8);

    // bf16 conversions
    {
        int n4 = M * 768 / 4;
        f2b_flat<<<(n4 + 255) / 256, 256, 0, stream>>>(x, x_b, n4);
        n4 = Mn * 768 / 4;
        f2b_flat<<<(n4 + 255) / 256, 256, 0, stream>>>(context, ctx_b, n4);
        f2b_t<<<dim3(768 / 32, 768 / 32), tblk, 0, stream>>>(Wq, Wq_t, 768, 768);
        f2b_t<<<dim3(768 / 32, 768 / 32), tblk, 0, stream>>>(Wk, Wk_t, 768, 768);
        f2b_t<<<dim3(4096 / 32, 768 / 32), tblk, 0, stream>>>(Wv1, Wv1_t, 768, 4096);
        f2b_t<<<dim3(768 / 32, 768 / 32), tblk, 0, stream>>>(Wout, Wout_t, 768, 768);
    }

    // q = x @ Wq (bf16 out); k = context @ Wk (bf16 out)
    gemm_bt<true><<<dim3(768 / 128, M / 128), 256, 0, stream>>>(x_b, Wq_t, qb, M, 768, 768);
    gemm_bt<true><<<dim3(768 / 128, Mn / 128), 256, 0, stream>>>(ctx_b, Wk_t, kb, Mn, 768, 768);
    // h1 = context @ Wv1  (bf16 out, pre-LayerNorm)
    gemm_bt<true><<<dim3(4096 / 128, Mn / 128), 256, 0, stream>>>(ctx_b, Wv1_t, h1b, Mn, 4096, 768);
    // LN row stats of h1
    rowstat_h1<<<Mn, 256, 0, stream>>>(h1b, muh, rstdh);
    // S = QK^T * scale
    scores_mfma<<<dim3(n / 128, b * 8), 256, 0, stream>>>(qb, kb, S, n);
    // softmax stats
    rowstat<<<b * 8 * 64, 256, 0, stream>>>(S, mstat, lstat, n);
    // A = softmax(S) . LN(h1)  (LN + normalization folded)
    const size_t smem_bytes = (size_t)(8 * n + 2 * n) * sizeof(float);
    attn_vmid_ln<<<b * 64, 256, smem_bytes, stream>>>(S, mstat, lstat, muh, rstdh,
                                                      h1b, ln_g, ln_b, Abuf, n);
    // out_pre = A . Wc (bf16 out)
    apply_wc<<<b * 64, 768, 0, stream>>>(Abuf, Wc, outp_b);
    // out = out_pre @ Wout
    gemm_bt<false><<<dim3(768 / 128, M / 128), 256, 0, stream>>>(outp_b, Wout_t, out, M, 768, 768);
}

// Round 6
// 219.219 us; speedup vs baseline: 1.2786x; 1.2786x over previous
//
#include <hip/hip_runtime.h>
#include <math.h>

typedef unsigned short ushort_t;
typedef __bf16 bf16x8 __attribute__((ext_vector_type(8)));
typedef float f32x4 __attribute__((ext_vector_type(4)));

// ---------------------------------------------------------------------------
// fp32 <-> bf16 helpers
// ---------------------------------------------------------------------------
__device__ __forceinline__ ushort_t f2b_rne(float f) {
    union { float f; unsigned int u; } c;
    c.f = f;
    unsigned int u = c.u;
    u += 0x7FFFu + ((u >> 16) & 1u);
    return (ushort_t)(u >> 16);
}
__device__ __forceinline__ float b2f(ushort_t v) {
    union { unsigned int u; float f; } c;
    c.u = ((unsigned int)v) << 16;
    return c.f;
}

// ---------------------------------------------------------------------------
// prep: ALL bf16 conversions in one dispatch (blockIdx-region dispatch).
//   region 0: x flat convert            (b*64*768/4/256 blocks)
//   region 1: context flat convert      (b*n*768/4/256 blocks)
//   region 2: Wq^T, Wk^T, Wv1^T, Wout^T (32x32 transpose tiles)
// ---------------------------------------------------------------------------
__global__ __launch_bounds__(256) void prep(
    const float* __restrict__ x, const float* __restrict__ context,
    const float* __restrict__ Wq, const float* __restrict__ Wk,
    const float* __restrict__ Wv1, const float* __restrict__ Wout,
    ushort_t* __restrict__ x_b, ushort_t* __restrict__ ctx_b,
    ushort_t* __restrict__ Wq_t, ushort_t* __restrict__ Wk_t,
    ushort_t* __restrict__ Wv1_t, ushort_t* __restrict__ Wout_t,
    int b, int n) {
    const int t = threadIdx.x;
    const int bid = blockIdx.x;
    const int nb_x = (b * 64 * 768 / 4) / 256;
    const int nb_c = (b * n * 768 / 4) / 256;

    if (bid < nb_x + nb_c) {  // flat converts
        const float* in = (bid < nb_x) ? x : context;
        ushort_t* outp = (bid < nb_x) ? x_b : ctx_b;
        const int i = ((bid < nb_x) ? bid : (bid - nb_x)) * 256 + t;
        float4 v = ((const float4*)in)[i];
        ushort_t o[4] = {f2b_rne(v.x), f2b_rne(v.y), f2b_rne(v.z), f2b_rne(v.w)};
        *(uint2*)&outp[(size_t)i * 4] = *(uint2*)o;
        return;
    }

    // transposes: Wq 576, Wk 576, Wv1 (4096/32)*(768/32)=3072, Wout 576
    int u = bid - nb_x - nb_c;
    const float* in;
    ushort_t* outp;
    int R = 768, C = 768;
    if (u < 576)        { in = Wq;  outp = Wq_t; }
    else if (u < 1152)  { u -= 576;  in = Wk;  outp = Wk_t; }
    else if (u < 4224)  { u -= 1152; in = Wv1; outp = Wv1_t; C = 4096; }
    else                { u -= 4224; in = Wout; outp = Wout_t; }
    const int ct = C / 32;
    const int c0 = (u % ct) * 32, r0 = (u / ct) * 32;
    const int tx = t & 31, ty = t >> 5;

    __shared__ float tt[32][33];
#pragma unroll
    for (int i = 0; i < 4; i++)
        tt[ty + 8 * i][tx] = in[(size_t)(r0 + ty + 8 * i) * C + c0 + tx];
    __syncthreads();
#pragma unroll
    for (int i = 0; i < 4; i++)
        outp[(size_t)(c0 + ty + 8 * i) * R + r0 + tx] = f2b_rne(tt[tx][ty + 8 * i]);
}

// ---------------------------------------------------------------------------
// gemm3: q, k, h1 GEMMs fused via flattened tile list. All bf16 in/out,
// K=768. 128x128 tile, 4 waves, BK=32, mfma_f32_16x16x32_bf16.
// ---------------------------------------------------------------------------
__global__ __launch_bounds__(256) void gemm3(
    const ushort_t* __restrict__ x_b, const ushort_t* __restrict__ ctx_b,
    const ushort_t* __restrict__ Wq_t, const ushort_t* __restrict__ Wk_t,
    const ushort_t* __restrict__ Wv1_t,
    ushort_t* __restrict__ qb, ushort_t* __restrict__ kb,
    ushort_t* __restrict__ h1b, int b, int n) {
    const int bid = blockIdx.x;
    const int tq = (b * 64 / 128) * 6;            // q tiles
    const int tk = (b * n / 128) * 6;             // k tiles

    const ushort_t *A, *Bt;
    ushort_t* C;
    int N, row0, col0;
    if (bid < tq) {
        A = x_b; Bt = Wq_t; C = qb; N = 768;
        row0 = (bid / 6) * 128; col0 = (bid % 6) * 128;
    } else if (bid < tq + tk) {
        const int u = bid - tq;
        A = ctx_b; Bt = Wk_t; C = kb; N = 768;
        row0 = (u / 6) * 128; col0 = (u % 6) * 128;
    } else {
        const int u = bid - tq - tk;
        A = ctx_b; Bt = Wv1_t; C = h1b; N = 4096;
        row0 = (u / 32) * 128; col0 = (u % 32) * 128;
    }
    const int K = 768;

    __shared__ ushort_t As[128 * 40];
    __shared__ ushort_t Bs[128 * 40];

    const int t = threadIdx.x;
    const int lane = t & 63;
    const int wave = t >> 6;
    const int quad = lane >> 4;
    const int l15 = lane & 15;
    const int wm = (wave >> 1) * 64;
    const int wn = (wave & 1) * 64;

    const int srow = t >> 2;
    const int sseg = t & 3;
    const ushort_t* ga0 = A + (size_t)(row0 + srow) * K + sseg * 8;
    const ushort_t* ga1 = A + (size_t)(row0 + srow + 64) * K + sseg * 8;
    const ushort_t* gb0 = Bt + (size_t)(col0 + srow) * K + sseg * 8;
    const ushort_t* gb1 = Bt + (size_t)(col0 + srow + 64) * K + sseg * 8;

    f32x4 acc[4][4] = {};

    bf16x8 ra0 = *(const bf16x8*)ga0;
    bf16x8 ra1 = *(const bf16x8*)ga1;
    bf16x8 rb0 = *(const bf16x8*)gb0;
    bf16x8 rb1 = *(const bf16x8*)gb1;

    for (int k0 = 0; k0 < K; k0 += 32) {
        __syncthreads();
        *(bf16x8*)&As[srow * 40 + sseg * 8] = ra0;
        *(bf16x8*)&As[(srow + 64) * 40 + sseg * 8] = ra1;
        *(bf16x8*)&Bs[srow * 40 + sseg * 8] = rb0;
        *(bf16x8*)&Bs[(srow + 64) * 40 + sseg * 8] = rb1;
        __syncthreads();
        if (k0 + 32 < K) {
            ra0 = *(const bf16x8*)(ga0 + k0 + 32);
            ra1 = *(const bf16x8*)(ga1 + k0 + 32);
            rb0 = *(const bf16x8*)(gb0 + k0 + 32);
            rb1 = *(const bf16x8*)(gb1 + k0 + 32);
        }
        bf16x8 af[4], bfr[4];
#pragma unroll
        for (int i = 0; i < 4; i++)
            af[i] = *(const bf16x8*)&As[(wm + i * 16 + l15) * 40 + quad * 8];
#pragma unroll
        for (int j = 0; j < 4; j++)
            bfr[j] = *(const bf16x8*)&Bs[(wn + j * 16 + l15) * 40 + quad * 8];
#pragma unroll
        for (int i = 0; i < 4; i++)
#pragma unroll
            for (int j = 0; j < 4; j++)
                acc[i][j] = __builtin_amdgcn_mfma_f32_16x16x32_bf16(
                    af[i], bfr[j], acc[i][j], 0, 0, 0);
    }

#pragma unroll
    for (int i = 0; i < 4; i++)
#pragma unroll
        for (int j = 0; j < 4; j++)
#pragma unroll
            for (int r = 0; r < 4; r++) {
                const int row = row0 + wm + i * 16 + quad * 4 + r;
                const int col = col0 + wn + j * 16 + l15;
                C[(size_t)row * N + col] = f2b_rne(acc[i][j][r]);
            }
}

// ---------------------------------------------------------------------------
// stats_scores: fuses rowstat_h1 (LN mu/rstd per h1 row) and scores_mfma
// (S = QK^T/sqrt(96)). Both depend only on gemm3.
//   bid <  b*n          : LN stats of h1 row bid
//   bid >= b*n          : scores tile
// ---------------------------------------------------------------------------
__global__ __launch_bounds__(256) void stats_scores(
    const ushort_t* __restrict__ h1b, const ushort_t* __restrict__ qb,
    const ushort_t* __restrict__ kb, float* __restrict__ mu,
    float* __restrict__ rstd, float* __restrict__ S, int b, int n) {
    __shared__ ushort_t sb[192 * 104];  // scores: Qs|Ks. rowstat: reduce buf.
    const int bid = blockIdx.x;
    const int t = threadIdx.x;

    if (bid < b * n) {  // ---- LN row stats ----
        float* red = (float*)sb;
        const ushort_t* p = h1b + (size_t)bid * 4096;
        float v[16];
#pragma unroll
        for (int g = 0; g < 2; g++) {
            bf16x8 xv = *(const bf16x8*)&p[(t + g * 256) * 8];
#pragma unroll
            for (int j = 0; j < 8; j++) v[g * 8 + j] = (float)xv[j];
        }
        float s = 0.f;
#pragma unroll
        for (int i = 0; i < 16; i++) s += v[i];
        red[t] = s;
        __syncthreads();
        for (int off = 128; off > 0; off >>= 1) {
            if (t < off) red[t] += red[t + off];
            __syncthreads();
        }
        const float m = red[0] * (1.0f / 4096.0f);
        __syncthreads();
        float s2 = 0.f;
#pragma unroll
        for (int i = 0; i < 16; i++) { const float d = v[i] - m; s2 += d * d; }
        red[t] = s2;
        __syncthreads();
        for (int off = 128; off > 0; off >>= 1) {
            if (t < off) red[t] += red[t + off];
            __syncthreads();
        }
        if (t == 0) {
            mu[bid] = m;
            rstd[bid] = rsqrtf(red[0] * (1.0f / 4096.0f) + 1e-5f);
        }
        return;
    }

    // ---- scores tile ----
    const int sid = bid - b * n;
    const int nt = n / 128;
    const int n0 = (sid % nt) * 128;
    const int bh = sid / nt;
    const int bb = bh >> 3, h = bh & 7;
    const int lane = t & 63, wave = t >> 6;
    const int quad = lane >> 4, l15 = lane & 15;
    const int wm = (wave >> 1) * 32;
    const int wn = (wave & 1) * 64;

    ushort_t* Qs = sb;
    ushort_t* Ks = sb + 64 * 104;

    for (int g = t; g < 768; g += 256) {
        const int r = g / 12, s = g - r * 12;
        *(bf16x8*)&Qs[r * 104 + s * 8] =
            *(const bf16x8*)&qb[(size_t)(bb * 64 + r) * 768 + h * 96 + s * 8];
    }
    for (int g = t; g < 1536; g += 256) {
        const int r = g / 12, s = g - r * 12;
        *(bf16x8*)&Ks[r * 104 + s * 8] =
            *(const bf16x8*)&kb[(size_t)(bb * n + n0 + r) * 768 + h * 96 + s * 8];
    }
    __syncthreads();

    f32x4 acc[2][4] = {};
#pragma unroll
    for (int ks = 0; ks < 3; ks++) {
        bf16x8 af[2], bfr[4];
#pragma unroll
        for (int i = 0; i < 2; i++)
            af[i] = *(const bf16x8*)&Qs[(wm + i * 16 + l15) * 104 + ks * 32 + quad * 8];
#pragma unroll
        for (int j = 0; j < 4; j++)
            bfr[j] = *(const bf16x8*)&Ks[(wn + j * 16 + l15) * 104 + ks * 32 + quad * 8];
#pragma unroll
        for (int i = 0; i < 2; i++)
#pragma unroll
            for (int j = 0; j < 4; j++)
                acc[i][j] = __builtin_amdgcn_mfma_f32_16x16x32_bf16(
                    af[i], bfr[j], acc[i][j], 0, 0, 0);
    }

    const float sc = 0.10206207261596575f;  // 1/sqrt(96)
    float* Sp = S + (size_t)bh * 64 * n;
#pragma unroll
    for (int i = 0; i < 2; i++)
#pragma unroll
        for (int j = 0; j < 4; j++)
#pragma unroll
            for (int r = 0; r < 4; r++) {
                const int row = wm + i * 16 + quad * 4 + r;
                const int col = n0 + wn + j * 16 + l15;
                Sp[(size_t)row * n + col] = acc[i][j][r] * sc;
            }
}

// ---------------------------------------------------------------------------
// attn_pv: per (b,qi, n-chunk of 256): chunk-local online softmax stats +
// partial A = sum_k exp(S-m)*rstd_k*h1[k, qi*64+r], partial wmu, l.
// Grid (nsp, b*64), 256 thr. Output row: [0..511]=A, [512..519]=m,
// [520..527]=l, [528..535]=wmu (row stride 544 floats).
// ---------------------------------------------------------------------------
__global__ __launch_bounds__(256) void attn_pv(
    const float* __restrict__ S, const float* __restrict__ mu,
    const float* __restrict__ rstd, const ushort_t* __restrict__ h1b,
    float* __restrict__ Apart, int n, int nsp) {
    const int sp = blockIdx.x;
    const int bq = blockIdx.y;
    const int bb = bq >> 6, qi = bq & 63;
    const int k0 = sp * 256;
    const int tid = threadIdx.x;
    const int lane = tid & 63, wave = tid >> 6;

    __shared__ float sS[2048];   // w[8][256]; later reused as reduce[4][512]
    __shared__ float cw[32];
    __shared__ float sm[8], sl[8], swmu[8];

    // load S chunk: sS[h][k] = S[b,h,qi,k0+k]
    const size_t Sbase = ((size_t)(bb * 512) + qi) * n + k0;
#pragma unroll
    for (int h = 0; h < 8; h++)
        sS[h * 256 + tid] = S[Sbase + (size_t)h * 64 * n + tid];
    const float mu_t = mu[(size_t)bb * n + k0 + tid];
    const float rs_t = rstd[(size_t)bb * n + k0 + tid];
    __syncthreads();

    // chunk-local max per h
#pragma unroll
    for (int h = 0; h < 8; h++) {
        float v = sS[h * 256 + tid];
        for (int off = 32; off > 0; off >>= 1) v = fmaxf(v, __shfl_down(v, off));
        if (lane == 0) cw[wave * 8 + h] = v;
    }
    __syncthreads();
    if (tid < 8)
        sm[tid] = fmaxf(fmaxf(cw[tid], cw[8 + tid]), fmaxf(cw[16 + tid], cw[24 + tid]));
    __syncthreads();

    // w = exp(S-m)*rstd (in place); partial l and wmu
    float lp[8], wp[8];
#pragma unroll
    for (int h = 0; h < 8; h++) {
        const float e = expf(sS[h * 256 + tid] - sm[h]);
        const float w = e * rs_t;
        sS[h * 256 + tid] = w;
        lp[h] = e;
        wp[h] = w * mu_t;
    }
#pragma unroll
    for (int h = 0; h < 8; h++) {
        float v = lp[h];
        for (int off = 32; off > 0; off >>= 1) v += __shfl_down(v, off);
        if (lane == 0) cw[wave * 8 + h] = v;
    }
    __syncthreads();
    if (tid < 8) sl[tid] = cw[tid] + cw[8 + tid] + cw[16 + tid] + cw[24 + tid];
    __syncthreads();
#pragma unroll
    for (int h = 0; h < 8; h++) {
        float v = wp[h];
        for (int off = 32; off > 0; off >>= 1) v += __shfl_down(v, off);
        if (lane == 0) cw[wave * 8 + h] = v;
    }
    __syncthreads();
    if (tid < 8) swmu[tid] = cw[tid] + cw[8 + tid] + cw[16 + tid] + cw[24 + tid];

    // main: wave (=cgrp) streams 64 rows of h1, r = lane
    const int r = lane, cgrp = wave;
    const ushort_t* vp =
        h1b + ((size_t)bb * n + k0 + cgrp * 64) * 4096 + qi * 64 + r;
    float acc[8] = {};
    for (int o = 0; o < 64; o += 4) {
        const float v0 = b2f(vp[(size_t)(o + 0) * 4096]);
        const float v1 = b2f(vp[(size_t)(o + 1) * 4096]);
        const float v2 = b2f(vp[(size_t)(o + 2) * 4096]);
        const float v3 = b2f(vp[(size_t)(o + 3) * 4096]);
#pragma unroll
        for (int h = 0; h < 8; h++) {
            const float4 w4 = *(const float4*)&sS[h * 256 + cgrp * 64 + o];
            acc[h] += w4.x * v0 + w4.y * v1 + w4.z * v2 + w4.w * v3;
        }
    }
    __syncthreads();
#pragma unroll
    for (int h = 0; h < 8; h++) sS[cgrp * 512 + h * 64 + r] = acc[h];
    __syncthreads();

    float* Ap = Apart + ((size_t)bq * nsp + sp) * 544;
#pragma unroll
    for (int s = 0; s < 2; s++) {
        const int o = tid + s * 256;
        Ap[o] = sS[o] + sS[512 + o] + sS[1024 + o] + sS[1536 + o];
    }
    if (tid < 8) {
        Ap[512 + tid] = sm[tid];
        Ap[520 + tid] = sl[tid];
        Ap[528 + tid] = swmu[tid];
    }
}

// ---------------------------------------------------------------------------
// merge_wc: merge chunk partials (online-softmax rescale), LN affine, then
// out_pre[d] = sum_r A[h(d)][r] * Wc[qi,r,d] (bf16 out). Grid b*64.
// ---------------------------------------------------------------------------
__global__ __launch_bounds__(256) void merge_wc(
    const float* __restrict__ Apart, const float* __restrict__ ln_g,
    const float* __restrict__ ln_b, const float* __restrict__ Wc,
    ushort_t* __restrict__ outp, int nsp) {
    const int bq = blockIdx.x;
    const int qi = bq & 63;
    const int tid = threadIdx.x;

    __shared__ float sA[512];
    __shared__ float sst[8 * 24];  // per sp: m[8], l[8], wmu[8]

    for (int i = tid; i < nsp * 24; i += 256) {
        const int sp = i / 24, j = i - sp * 24;
        sst[sp * 24 + j] = Apart[((size_t)bq * nsp + sp) * 544 + 512 + j];
    }
    __syncthreads();

#pragma unroll
    for (int s = 0; s < 2; s++) {
        const int o = tid + s * 256;
        const int h = o >> 6, rr = o & 63;
        float m = -1e30f;
        for (int sp = 0; sp < nsp; sp++) m = fmaxf(m, sst[sp * 24 + h]);
        float l = 0.f, wm = 0.f, v = 0.f;
        for (int sp = 0; sp < nsp; sp++) {
            const float scl = expf(sst[sp * 24 + h] - m);
            l += scl * sst[sp * 24 + 8 + h];
            wm += scl * sst[sp * 24 + 16 + h];
            v += scl * Apart[((size_t)bq * nsp + sp) * 544 + o];
        }
        const int c = qi * 64 + rr;
        sA[o] = ln_g[c] * ((v - wm) / l) + ln_b[c];
    }
    __syncthreads();

    for (int d = tid; d < 768; d += 256) {
        const int h = d / 96;
        const float* wp = Wc + (size_t)qi * 49152 + d;
        float a = 0.f;
#pragma unroll
        for (int r = 0; r < 64; r++) a += sA[h * 64 + r] * wp[(size_t)r * 768];
        outp[(size_t)bq * 768 + d] = f2b_rne(a);
    }
}

// ---------------------------------------------------------------------------
// Final out = outp_b @ Wout_t^T, fp32 out. Same 128x128 MFMA tile.
// ---------------------------------------------------------------------------
__global__ __launch_bounds__(256) void gemm_out(const ushort_t* __restrict__ A,
                                                const ushort_t* __restrict__ Bt,
                                                float* __restrict__ C,
                                                int M, int N, int K) {
    __shared__ ushort_t As[128 * 40];
    __shared__ ushort_t Bs[128 * 40];

    const int t = threadIdx.x;
    const int lane = t & 63;
    const int wave = t >> 6;
    const int quad = lane >> 4;
    const int l15 = lane & 15;
    const int wm = (wave >> 1) * 64;
    const int wn = (wave & 1) * 64;
    const int row0 = blockIdx.y * 128, col0 = blockIdx.x * 128;

    const int srow = t >> 2;
    const int sseg = t & 3;
    const ushort_t* ga0 = A + (size_t)(row0 + srow) * K + sseg * 8;
    const ushort_t* ga1 = A + (size_t)(row0 + srow + 64) * K + sseg * 8;
    const ushort_t* gb0 = Bt + (size_t)(col0 + srow) * K + sseg * 8;
    const ushort_t* gb1 = Bt + (size_t)(col0 + srow + 64) * K + sseg * 8;

    f32x4 acc[4][4] = {};

    bf16x8 ra0 = *(const bf16x8*)ga0;
    bf16x8 ra1 = *(const bf16x8*)ga1;
    bf16x8 rb0 = *(const bf16x8*)gb0;
    bf16x8 rb1 = *(const bf16x8*)gb1;

    for (int k0 = 0; k0 < K; k0 += 32) {
        __syncthreads();
        *(bf16x8*)&As[srow * 40 + sseg * 8] = ra0;
        *(bf16x8*)&As[(srow + 64) * 40 + sseg * 8] = ra1;
        *(bf16x8*)&Bs[srow * 40 + sseg * 8] = rb0;
        *(bf16x8*)&Bs[(srow + 64) * 40 + sseg * 8] = rb1;
        __syncthreads();
        if (k0 + 32 < K) {
            ra0 = *(const bf16x8*)(ga0 + k0 + 32);
            ra1 = *(const bf16x8*)(ga1 + k0 + 32);
            rb0 = *(const bf16x8*)(gb0 + k0 + 32);
            rb1 = *(const bf16x8*)(gb1 + k0 + 32);
        }
        bf16x8 af[4], bfr[4];
#pragma unroll
        for (int i = 0; i < 4; i++)
            af[i] = *(const bf16x8*)&As[(wm + i * 16 + l15) * 40 + quad * 8];
#pragma unroll
        for (int j = 0; j < 4; j++)
            bfr[j] = *(const bf16x8*)&Bs[(wn + j * 16 + l15) * 40 + quad * 8];
#pragma unroll
        for (int i = 0; i < 4; i++)
#pragma unroll
            for (int j = 0; j < 4; j++)
                acc[i][j] = __builtin_amdgcn_mfma_f32_16x16x32_bf16(
                    af[i], bfr[j], acc[i][j], 0, 0, 0);
    }

#pragma unroll
    for (int i = 0; i < 4; i++)
#pragma unroll
        for (int j = 0; j < 4; j++)
#pragma unroll
            for (int r = 0; r < 4; r++) {
                const int row = row0 + wm + i * 16 + quad * 4 + r;
                const int col = col0 + wn + j * 16 + l15;
                C[(size_t)row * N + col] = acc[i][j][r];
            }
}

// ---------------------------------------------------------------------------
extern "C" void kernel_launch(void* const* d_in, const int* in_sizes, int n_in,
                              void* d_out, int out_size, void* d_ws, size_t ws_size,
                              hipStream_t stream) {
    const float* x       = (const float*)d_in[0];
    const float* context = (const float*)d_in[1];
    const float* Wq      = (const float*)d_in[2];
    const float* Wk      = (const float*)d_in[3];
    const float* Wv1     = (const float*)d_in[4];
    const float* ln_g    = (const float*)d_in[5];
    const float* ln_b    = (const float*)d_in[6];
    const float* Wc      = (const float*)d_in[7];
    const float* Wout    = (const float*)d_in[8];
    float* out = (float*)d_out;

    const int b = in_sizes[0] / (64 * 768);
    const int n = in_sizes[1] / (b * 768);
    const int M  = b * 64;     // 256
    const int Mn = b * n;      // 4096
    const int nsp = n / 256;   // 4

    float* ws = (float*)d_ws;
    size_t off = 0;
    float* S     = ws + off;  off += (size_t)b * 8 * 64 * n;
    float* Apart = ws + off;  off += (size_t)M * nsp * 544;
    float* muh   = ws + off;  off += (size_t)Mn;
    float* rstdh = ws + off;  off += (size_t)Mn;

    ushort_t* us = (ushort_t*)(ws + off);
    size_t uo = 0;
    ushort_t* x_b    = us + uo;  uo += (size_t)M * 768;
    ushort_t* ctx_b  = us + uo;  uo += (size_t)Mn * 768;
    ushort_t* qb     = us + uo;  uo += (size_t)M * 768;
    ushort_t* kb     = us + uo;  uo += (size_t)Mn * 768;
    ushort_t* h1b    = us + uo;  uo += (size_t)Mn * 4096;
    ushort_t* Wq_t   = us + uo;  uo += (size_t)768 * 768;
    ushort_t* Wk_t   = us + uo;  uo += (size_t)768 * 768;
    ushort_t* Wv1_t  = us + uo;  uo += (size_t)4096 * 768;
    ushort_t* Wout_t = us + uo;  uo += (size_t)768 * 768;
    ushort_t* outp_b = us + uo;  uo += (size_t)M * 768;

    // 1. all conversions
    const int nb_x = (M * 768 / 4) / 256;
    const int nb_c = (Mn * 768 / 4) / 256;
    prep<<<nb_x + nb_c + 576 * 3 + 3072, 256, 0, stream>>>(
        x, context, Wq, Wk, Wv1, Wout, x_b, ctx_b, Wq_t, Wk_t, Wv1_t, Wout_t, b, n);

    // 2. q, k, h1 GEMMs fused
    const int tq = (M / 128) * 6, tk = (Mn / 128) * 6, th = (Mn / 128) * 32;
    gemm3<<<tq + tk + th, 256, 0, stream>>>(x_b, ctx_b, Wq_t, Wk_t, Wv1_t,
                                            qb, kb, h1b, b, n);

    // 3. LN row stats + scores fused
    stats_scores<<<Mn + b * 8 * (n / 128), 256, 0, stream>>>(
        h1b, qb, kb, muh, rstdh, S, b, n);

    // 4. chunked attention-V with online-softmax partials
    attn_pv<<<dim3(nsp, M), 256, 0, stream>>>(S, muh, rstdh, h1b, Apart, n, nsp);

    // 5. merge + LN affine + Wc
    merge_wc<<<M, 256, 0, stream>>>(Apart, ln_g, ln_b, Wc, outp_b, nsp);

    // 6. out = outp @ Wout
    gemm_out<<<dim3(6, M / 128), 256, 0, stream>>>(outp_b, Wout_t, out, M, 768, 768);
}

// Round 7
// 203.088 us; speedup vs baseline: 1.3801x; 1.0794x over previous
//
#include <hip/hip_runtime.h>
#include <math.h>

typedef unsigned short ushort_t;
typedef __bf16 bf16x8 __attribute__((ext_vector_type(8)));
typedef float f32x4 __attribute__((ext_vector_type(4)));

// ---------------------------------------------------------------------------
// fp32 <-> bf16 helpers
// ---------------------------------------------------------------------------
__device__ __forceinline__ ushort_t f2b_rne(float f) {
    union { float f; unsigned int u; } c;
    c.f = f;
    unsigned int u = c.u;
    u += 0x7FFFu + ((u >> 16) & 1u);
    return (ushort_t)(u >> 16);
}
__device__ __forceinline__ float b2f(ushort_t v) {
    union { unsigned int u; float f; } c;
    c.u = ((unsigned int)v) << 16;
    return c.f;
}

// async global->LDS DMA, 16B per lane. LDS dest = uniform base + lane*16.
__device__ __forceinline__ void gl_lds16(const ushort_t* g, ushort_t* l) {
    __builtin_amdgcn_global_load_lds(
        (const __attribute__((address_space(1))) void*)g,
        (__attribute__((address_space(3))) void*)l, 16, 0, 0);
}

// ---------------------------------------------------------------------------
// prep: ALL bf16 conversions in one dispatch (blockIdx-region dispatch).
// ---------------------------------------------------------------------------
__global__ __launch_bounds__(256) void prep(
    const float* __restrict__ x, const float* __restrict__ context,
    const float* __restrict__ Wq, const float* __restrict__ Wk,
    const float* __restrict__ Wv1, const float* __restrict__ Wout,
    ushort_t* __restrict__ x_b, ushort_t* __restrict__ ctx_b,
    ushort_t* __restrict__ Wq_t, ushort_t* __restrict__ Wk_t,
    ushort_t* __restrict__ Wv1_t, ushort_t* __restrict__ Wout_t,
    int b, int n) {
    const int t = threadIdx.x;
    const int bid = blockIdx.x;
    const int nb_x = (b * 64 * 768 / 4) / 256;
    const int nb_c = (b * n * 768 / 4) / 256;

    if (bid < nb_x + nb_c) {  // flat converts
        const float* in = (bid < nb_x) ? x : context;
        ushort_t* outp = (bid < nb_x) ? x_b : ctx_b;
        const int i = ((bid < nb_x) ? bid : (bid - nb_x)) * 256 + t;
        float4 v = ((const float4*)in)[i];
        ushort_t o[4] = {f2b_rne(v.x), f2b_rne(v.y), f2b_rne(v.z), f2b_rne(v.w)};
        *(uint2*)&outp[(size_t)i * 4] = *(uint2*)o;
        return;
    }

    // transposes: Wq 576, Wk 576, Wv1 3072, Wout 576
    int u = bid - nb_x - nb_c;
    const float* in;
    ushort_t* outp;
    int R = 768, C = 768;
    if (u < 576)        { in = Wq;  outp = Wq_t; }
    else if (u < 1152)  { u -= 576;  in = Wk;  outp = Wk_t; }
    else if (u < 4224)  { u -= 1152; in = Wv1; outp = Wv1_t; C = 4096; }
    else                { u -= 4224; in = Wout; outp = Wout_t; }
    const int ct = C / 32;
    const int c0 = (u % ct) * 32, r0 = (u / ct) * 32;
    const int tx = t & 31, ty = t >> 5;

    __shared__ float tt[32][33];
#pragma unroll
    for (int i = 0; i < 4; i++)
        tt[ty + 8 * i][tx] = in[(size_t)(r0 + ty + 8 * i) * C + c0 + tx];
    __syncthreads();
#pragma unroll
    for (int i = 0; i < 4; i++)
        outp[(size_t)(c0 + ty + 8 * i) * R + r0 + tx] = f2b_rne(tt[tx][ty + 8 * i]);
}

// ---------------------------------------------------------------------------
// gemm3: q, k, h1 GEMMs fused via flattened tile list. bf16 in/out, K=768.
// m97 structure: global_load_lds width=16 into unpadded [128][32] slabs.
// Slab coverage: 512 16B-units/operand; thread t handles units t and t+256;
// LDS base per wave-instr = As + (j*256 + wave*64)*8 elems (uniform), lane*16
// auto. Fragment ds_read_b128 granule distribution balanced (8-way floor).
// ---------------------------------------------------------------------------
__global__ __launch_bounds__(256) void gemm3(
    const ushort_t* __restrict__ x_b, const ushort_t* __restrict__ ctx_b,
    const ushort_t* __restrict__ Wq_t, const ushort_t* __restrict__ Wk_t,
    const ushort_t* __restrict__ Wv1_t,
    ushort_t* __restrict__ qb, ushort_t* __restrict__ kb,
    ushort_t* __restrict__ h1b, int b, int n) {
    const int bid = blockIdx.x;
    const int tq = (b * 64 / 128) * 6;
    const int tk = (b * n / 128) * 6;

    const ushort_t *A, *Bt;
    ushort_t* C;
    int N, row0, col0;
    if (bid < tq) {
        A = x_b; Bt = Wq_t; C = qb; N = 768;
        row0 = (bid / 6) * 128; col0 = (bid % 6) * 128;
    } else if (bid < tq + tk) {
        const int u = bid - tq;
        A = ctx_b; Bt = Wk_t; C = kb; N = 768;
        row0 = (u / 6) * 128; col0 = (u % 6) * 128;
    } else {
        const int u = bid - tq - tk;
        A = ctx_b; Bt = Wv1_t; C = h1b; N = 4096;
        row0 = (u / 32) * 128; col0 = (u % 32) * 128;
    }
    const int K = 768;

    __shared__ ushort_t As[128 * 32];
    __shared__ ushort_t Bs[128 * 32];

    const int t = threadIdx.x;
    const int lane = t & 63;
    const int wave = t >> 6;
    const int quad = lane >> 4;
    const int l15 = lane & 15;
    const int wm = (wave >> 1) * 64;
    const int wn = (wave & 1) * 64;

    // global pointers: unit t -> row t>>2, seg t&3; unit t+256 -> row +64
    const ushort_t* ga0 = A + (size_t)(row0 + (t >> 2)) * K + (t & 3) * 8;
    const ushort_t* ga1 = ga0 + (size_t)64 * K;
    const ushort_t* gb0 = Bt + (size_t)(col0 + (t >> 2)) * K + (t & 3) * 8;
    const ushort_t* gb1 = gb0 + (size_t)64 * K;

    ushort_t* lA0 = &As[wave * 512];           // units [wave*64 .. +64)
    ushort_t* lA1 = &As[2048 + wave * 512];    // units [256+wave*64 .. +64)
    ushort_t* lB0 = &Bs[wave * 512];
    ushort_t* lB1 = &Bs[2048 + wave * 512];

    f32x4 acc[4][4] = {};

    for (int k0 = 0; k0 < K; k0 += 32) {
        __syncthreads();
        gl_lds16(ga0 + k0, lA0);
        gl_lds16(ga1 + k0, lA1);
        gl_lds16(gb0 + k0, lB0);
        gl_lds16(gb1 + k0, lB1);
        __syncthreads();   // drains vmcnt -> DMA complete for all waves

        bf16x8 af[4], bfr[4];
#pragma unroll
        for (int i = 0; i < 4; i++)
            af[i] = *(const bf16x8*)&As[(wm + i * 16 + l15) * 32 + quad * 8];
#pragma unroll
        for (int j = 0; j < 4; j++)
            bfr[j] = *(const bf16x8*)&Bs[(wn + j * 16 + l15) * 32 + quad * 8];
#pragma unroll
        for (int i = 0; i < 4; i++)
#pragma unroll
            for (int j = 0; j < 4; j++)
                acc[i][j] = __builtin_amdgcn_mfma_f32_16x16x32_bf16(
                    af[i], bfr[j], acc[i][j], 0, 0, 0);
    }

    // C/D layout: col = lane&15, row = (lane>>4)*4 + reg   [m89/m91]
#pragma unroll
    for (int i = 0; i < 4; i++)
#pragma unroll
        for (int j = 0; j < 4; j++)
#pragma unroll
            for (int r = 0; r < 4; r++) {
                const int row = row0 + wm + i * 16 + quad * 4 + r;
                const int col = col0 + wn + j * 16 + l15;
                C[(size_t)row * N + col] = f2b_rne(acc[i][j][r]);
            }
}

// ---------------------------------------------------------------------------
// stats_scores: fuses rowstat_h1 (LN mu/rstd) and scores (S = QK^T/sqrt(96)).
// ---------------------------------------------------------------------------
__global__ __launch_bounds__(256) void stats_scores(
    const ushort_t* __restrict__ h1b, const ushort_t* __restrict__ qb,
    const ushort_t* __restrict__ kb, float* __restrict__ mu,
    float* __restrict__ rstd, float* __restrict__ S, int b, int n) {
    __shared__ ushort_t sb[192 * 104];
    const int bid = blockIdx.x;
    const int t = threadIdx.x;

    if (bid < b * n) {  // ---- LN row stats ----
        float* red = (float*)sb;
        const ushort_t* p = h1b + (size_t)bid * 4096;
        float v[16];
#pragma unroll
        for (int g = 0; g < 2; g++) {
            bf16x8 xv = *(const bf16x8*)&p[(t + g * 256) * 8];
#pragma unroll
            for (int j = 0; j < 8; j++) v[g * 8 + j] = (float)xv[j];
        }
        float s = 0.f;
#pragma unroll
        for (int i = 0; i < 16; i++) s += v[i];
        red[t] = s;
        __syncthreads();
        for (int off = 128; off > 0; off >>= 1) {
            if (t < off) red[t] += red[t + off];
            __syncthreads();
        }
        const float m = red[0] * (1.0f / 4096.0f);
        __syncthreads();
        float s2 = 0.f;
#pragma unroll
        for (int i = 0; i < 16; i++) { const float d = v[i] - m; s2 += d * d; }
        red[t] = s2;
        __syncthreads();
        for (int off = 128; off > 0; off >>= 1) {
            if (t < off) red[t] += red[t + off];
            __syncthreads();
        }
        if (t == 0) {
            mu[bid] = m;
            rstd[bid] = rsqrtf(red[0] * (1.0f / 4096.0f) + 1e-5f);
        }
        return;
    }

    // ---- scores tile ----
    const int sid = bid - b * n;
    const int nt = n / 128;
    const int n0 = (sid % nt) * 128;
    const int bh = sid / nt;
    const int bb = bh >> 3, h = bh & 7;
    const int lane = t & 63, wave = t >> 6;
    const int quad = lane >> 4, l15 = lane & 15;
    const int wm = (wave >> 1) * 32;
    const int wn = (wave & 1) * 64;

    ushort_t* Qs = sb;
    ushort_t* Ks = sb + 64 * 104;

    for (int g = t; g < 768; g += 256) {
        const int r = g / 12, s = g - r * 12;
        *(bf16x8*)&Qs[r * 104 + s * 8] =
            *(const bf16x8*)&qb[(size_t)(bb * 64 + r) * 768 + h * 96 + s * 8];
    }
    for (int g = t; g < 1536; g += 256) {
        const int r = g / 12, s = g - r * 12;
        *(bf16x8*)&Ks[r * 104 + s * 8] =
            *(const bf16x8*)&kb[(size_t)(bb * n + n0 + r) * 768 + h * 96 + s * 8];
    }
    __syncthreads();

    f32x4 acc[2][4] = {};
#pragma unroll
    for (int ks = 0; ks < 3; ks++) {
        bf16x8 af[2], bfr[4];
#pragma unroll
        for (int i = 0; i < 2; i++)
            af[i] = *(const bf16x8*)&Qs[(wm + i * 16 + l15) * 104 + ks * 32 + quad * 8];
#pragma unroll
        for (int j = 0; j < 4; j++)
            bfr[j] = *(const bf16x8*)&Ks[(wn + j * 16 + l15) * 104 + ks * 32 + quad * 8];
#pragma unroll
        for (int i = 0; i < 2; i++)
#pragma unroll
            for (int j = 0; j < 4; j++)
                acc[i][j] = __builtin_amdgcn_mfma_f32_16x16x32_bf16(
                    af[i], bfr[j], acc[i][j], 0, 0, 0);
    }

    const float sc = 0.10206207261596575f;  // 1/sqrt(96)
    float* Sp = S + (size_t)bh * 64 * n;
#pragma unroll
    for (int i = 0; i < 2; i++)
#pragma unroll
        for (int j = 0; j < 4; j++)
#pragma unroll
            for (int r = 0; r < 4; r++) {
                const int row = wm + i * 16 + quad * 4 + r;
                const int col = n0 + wn + j * 16 + l15;
                Sp[(size_t)row * n + col] = acc[i][j][r] * sc;
            }
}

// ---------------------------------------------------------------------------
// attn_pv: per (b,qi, n-chunk of 128): chunk-local softmax stats + partial
// A = sum_k exp(S-m)*rstd_k*h1[k, qi*64+r]; partial l, wmu.
// Grid (n/128, b*64), 256 thr, 8 blocks/CU. 8-deep load unroll.
// Output row [0..511]=A, [512..519]=m, [520..527]=l, [528..535]=wmu.
// ---------------------------------------------------------------------------
__global__ __launch_bounds__(256) void attn_pv(
    const float* __restrict__ S, const float* __restrict__ mu,
    const float* __restrict__ rstd, const ushort_t* __restrict__ h1b,
    float* __restrict__ Apart, int n, int nsp) {
    const int sp = blockIdx.x;
    const int bq = blockIdx.y;
    const int bb = bq >> 6, qi = bq & 63;
    const int k0 = sp * 128;
    const int tid = threadIdx.x;
    const int lane = tid & 63, w = tid >> 6;
    const int k = tid & 127, hg = tid >> 7;  // hg 0..1: handles h = hg*4..+4

    __shared__ float sS[2048];   // w[8][128] in [0..1024); reduce buf later
    __shared__ float smu[128], srs[128];
    __shared__ float cw[16];
    __shared__ float sm[8], sl[8], swmu[8];

    // stage S chunk and mu/rstd
    const size_t Sbase = ((size_t)(bb * 512) + qi) * n + k0;
    for (int i = tid; i < 1024; i += 256) {
        const int h = i >> 7, kk = i & 127;
        sS[i] = S[Sbase + (size_t)h * 64 * n + kk];
    }
    if (tid < 128) {
        smu[tid] = mu[(size_t)bb * n + k0 + tid];
        srs[tid] = rstd[(size_t)bb * n + k0 + tid];
    }
    __syncthreads();

    // chunk-local max per h (waves 2*hg, 2*hg+1 cover k halves)
    float r4[4];
#pragma unroll
    for (int hh = 0; hh < 4; hh++) r4[hh] = sS[(hg * 4 + hh) * 128 + k];
#pragma unroll
    for (int off = 32; off > 0; off >>= 1)
#pragma unroll
        for (int hh = 0; hh < 4; hh++) r4[hh] = fmaxf(r4[hh], __shfl_down(r4[hh], off));
    if (lane == 0)
#pragma unroll
        for (int hh = 0; hh < 4; hh++) cw[w * 4 + hh] = r4[hh];
    __syncthreads();
    if (tid < 8) {
        const int g2 = tid >> 2, hh = tid & 3;
        sm[tid] = fmaxf(cw[(2 * g2) * 4 + hh], cw[(2 * g2 + 1) * 4 + hh]);
    }
    __syncthreads();

    // w = exp(S-m)*rstd in place; partial l
    float wm4[4];
#pragma unroll
    for (int hh = 0; hh < 4; hh++) {
        const int h = hg * 4 + hh;
        const float e = expf(sS[h * 128 + k] - sm[h]);
        const float wv = e * srs[k];
        sS[h * 128 + k] = wv;
        r4[hh] = e;
        wm4[hh] = wv * smu[k];
    }
#pragma unroll
    for (int off = 32; off > 0; off >>= 1)
#pragma unroll
        for (int hh = 0; hh < 4; hh++) r4[hh] += __shfl_down(r4[hh], off);
    if (lane == 0)
#pragma unroll
        for (int hh = 0; hh < 4; hh++) cw[w * 4 + hh] = r4[hh];
    __syncthreads();
    if (tid < 8) {
        const int g2 = tid >> 2, hh = tid & 3;
        sl[tid] = cw[(2 * g2) * 4 + hh] + cw[(2 * g2 + 1) * 4 + hh];
    }
    __syncthreads();
#pragma unroll
    for (int off = 32; off > 0; off >>= 1)
#pragma unroll
        for (int hh = 0; hh < 4; hh++) wm4[hh] += __shfl_down(wm4[hh], off);
    if (lane == 0)
#pragma unroll
        for (int hh = 0; hh < 4; hh++) cw[w * 4 + hh] = wm4[hh];
    __syncthreads();
    if (tid < 8) {
        const int g2 = tid >> 2, hh = tid & 3;
        swmu[tid] = cw[(2 * g2) * 4 + hh] + cw[(2 * g2 + 1) * 4 + hh];
    }

    // main: wave w streams rows [k0+w*32, +32), r = lane. 8 loads in flight.
    const ushort_t* vp =
        h1b + ((size_t)bb * n + k0 + w * 32) * 4096 + qi * 64 + lane;
    float acc[8] = {};
    for (int o = 0; o < 32; o += 8) {
        float v[8];
#pragma unroll
        for (int j = 0; j < 8; j++) v[j] = b2f(vp[(size_t)(o + j) * 4096]);
#pragma unroll
        for (int h = 0; h < 8; h++) {
            const float4 wa = *(const float4*)&sS[h * 128 + w * 32 + o];
            const float4 wb = *(const float4*)&sS[h * 128 + w * 32 + o + 4];
            acc[h] += wa.x * v[0] + wa.y * v[1] + wa.z * v[2] + wa.w * v[3] +
                      wb.x * v[4] + wb.y * v[5] + wb.z * v[6] + wb.w * v[7];
        }
    }
    __syncthreads();
#pragma unroll
    for (int h = 0; h < 8; h++) sS[w * 512 + h * 64 + lane] = acc[h];
    __syncthreads();

    float* Ap = Apart + ((size_t)bq * nsp + sp) * 544;
#pragma unroll
    for (int s = 0; s < 2; s++) {
        const int o = tid + s * 256;
        Ap[o] = sS[o] + sS[512 + o] + sS[1024 + o] + sS[1536 + o];
    }
    if (tid < 8) {
        Ap[512 + tid] = sm[tid];
        Ap[520 + tid] = sl[tid];
        Ap[528 + tid] = swmu[tid];
    }
}

// ---------------------------------------------------------------------------
// merge_wc: merge chunk partials (online-softmax rescale), LN affine, Wc.
// ---------------------------------------------------------------------------
__global__ __launch_bounds__(256) void merge_wc(
    const float* __restrict__ Apart, const float* __restrict__ ln_g,
    const float* __restrict__ ln_b, const float* __restrict__ Wc,
    ushort_t* __restrict__ outp, int nsp) {
    const int bq = blockIdx.x;
    const int qi = bq & 63;
    const int tid = threadIdx.x;

    __shared__ float sA[512];
    __shared__ float sst[8 * 24];  // per sp: m[8], l[8], wmu[8]

    for (int i = tid; i < nsp * 24; i += 256) {
        const int sp = i / 24, j = i - sp * 24;
        sst[sp * 24 + j] = Apart[((size_t)bq * nsp + sp) * 544 + 512 + j];
    }
    __syncthreads();

#pragma unroll
    for (int s = 0; s < 2; s++) {
        const int o = tid + s * 256;
        const int h = o >> 6, rr = o & 63;
        float m = -1e30f;
        for (int sp = 0; sp < nsp; sp++) m = fmaxf(m, sst[sp * 24 + h]);
        float l = 0.f, wm = 0.f, v = 0.f;
        for (int sp = 0; sp < nsp; sp++) {
            const float scl = expf(sst[sp * 24 + h] - m);
            l += scl * sst[sp * 24 + 8 + h];
            wm += scl * sst[sp * 24 + 16 + h];
            v += scl * Apart[((size_t)bq * nsp + sp) * 544 + o];
        }
        const int c = qi * 64 + rr;
        sA[o] = ln_g[c] * ((v - wm) / l) + ln_b[c];
    }
    __syncthreads();

    for (int d = tid; d < 768; d += 256) {
        const int h = d / 96;
        const float* wp = Wc + (size_t)qi * 49152 + d;
        float a = 0.f;
#pragma unroll
        for (int r = 0; r < 64; r++) a += sA[h * 64 + r] * wp[(size_t)r * 768];
        outp[(size_t)bq * 768 + d] = f2b_rne(a);
    }
}

// ---------------------------------------------------------------------------
// Final out = outp_b @ Wout_t^T, fp32 out (2 blocks; manual staging fine).
// ---------------------------------------------------------------------------
__global__ __launch_bounds__(256) void gemm_out(const ushort_t* __restrict__ A,
                                                const ushort_t* __restrict__ Bt,
                                                float* __restrict__ C,
                                                int M, int N, int K) {
    __shared__ ushort_t As[128 * 40];
    __shared__ ushort_t Bs[128 * 40];

    const int t = threadIdx.x;
    const int lane = t & 63;
    const int wave = t >> 6;
    const int quad = lane >> 4;
    const int l15 = lane & 15;
    const int wm = (wave >> 1) * 64;
    const int wn = (wave & 1) * 64;
    const int row0 = blockIdx.y * 128, col0 = blockIdx.x * 128;

    const int srow = t >> 2;
    const int sseg = t & 3;
    const ushort_t* ga0 = A + (size_t)(row0 + srow) * K + sseg * 8;
    const ushort_t* ga1 = A + (size_t)(row0 + srow + 64) * K + sseg * 8;
    const ushort_t* gb0 = Bt + (size_t)(col0 + srow) * K + sseg * 8;
    const ushort_t* gb1 = Bt + (size_t)(col0 + srow + 64) * K + sseg * 8;

    f32x4 acc[4][4] = {};

    bf16x8 ra0 = *(const bf16x8*)ga0;
    bf16x8 ra1 = *(const bf16x8*)ga1;
    bf16x8 rb0 = *(const bf16x8*)gb0;
    bf16x8 rb1 = *(const bf16x8*)gb1;

    for (int k0 = 0; k0 < K; k0 += 32) {
        __syncthreads();
        *(bf16x8*)&As[srow * 40 + sseg * 8] = ra0;
        *(bf16x8*)&As[(srow + 64) * 40 + sseg * 8] = ra1;
        *(bf16x8*)&Bs[srow * 40 + sseg * 8] = rb0;
        *(bf16x8*)&Bs[(srow + 64) * 40 + sseg * 8] = rb1;
        __syncthreads();
        if (k0 + 32 < K) {
            ra0 = *(const bf16x8*)(ga0 + k0 + 32);
            ra1 = *(const bf16x8*)(ga1 + k0 + 32);
            rb0 = *(const bf16x8*)(gb0 + k0 + 32);
            rb1 = *(const bf16x8*)(gb1 + k0 + 32);
        }
        bf16x8 af[4], bfr[4];
#pragma unroll
        for (int i = 0; i < 4; i++)
            af[i] = *(const bf16x8*)&As[(wm + i * 16 + l15) * 40 + quad * 8];
#pragma unroll
        for (int j = 0; j < 4; j++)
            bfr[j] = *(const bf16x8*)&Bs[(wn + j * 16 + l15) * 40 + quad * 8];
#pragma unroll
        for (int i = 0; i < 4; i++)
#pragma unroll
            for (int j = 0; j < 4; j++)
                acc[i][j] = __builtin_amdgcn_mfma_f32_16x16x32_bf16(
                    af[i], bfr[j], acc[i][j], 0, 0, 0);
    }

#pragma unroll
    for (int i = 0; i < 4; i++)
#pragma unroll
        for (int j = 0; j < 4; j++)
#pragma unroll
            for (int r = 0; r < 4; r++) {
                const int row = row0 + wm + i * 16 + quad * 4 + r;
                const int col = col0 + wn + j * 16 + l15;
                C[(size_t)row * N + col] = acc[i][j][r];
            }
}

// ---------------------------------------------------------------------------
extern "C" void kernel_launch(void* const* d_in, const int* in_sizes, int n_in,
                              void* d_out, int out_size, void* d_ws, size_t ws_size,
                              hipStream_t stream) {
    const float* x       = (const float*)d_in[0];
    const float* context = (const float*)d_in[1];
    const float* Wq      = (const float*)d_in[2];
    const float* Wk      = (const float*)d_in[3];
    const float* Wv1     = (const float*)d_in[4];
    const float* ln_g    = (const float*)d_in[5];
    const float* ln_b    = (const float*)d_in[6];
    const float* Wc      = (const float*)d_in[7];
    const float* Wout    = (const float*)d_in[8];
    float* out = (float*)d_out;

    const int b = in_sizes[0] / (64 * 768);
    const int n = in_sizes[1] / (b * 768);
    const int M  = b * 64;     // 256
    const int Mn = b * n;      // 4096
    const int nsp = n / 128;   // 8

    float* ws = (float*)d_ws;
    size_t off = 0;
    float* S     = ws + off;  off += (size_t)b * 8 * 64 * n;
    float* Apart = ws + off;  off += (size_t)M * nsp * 544;
    float* muh   = ws + off;  off += (size_t)Mn;
    float* rstdh = ws + off;  off += (size_t)Mn;

    ushort_t* us = (ushort_t*)(ws + off);
    size_t uo = 0;
    ushort_t* x_b    = us + uo;  uo += (size_t)M * 768;
    ushort_t* ctx_b  = us + uo;  uo += (size_t)Mn * 768;
    ushort_t* qb     = us + uo;  uo += (size_t)M * 768;
    ushort_t* kb     = us + uo;  uo += (size_t)Mn * 768;
    ushort_t* h1b    = us + uo;  uo += (size_t)Mn * 4096;
    ushort_t* Wq_t   = us + uo;  uo += (size_t)768 * 768;
    ushort_t* Wk_t   = us + uo;  uo += (size_t)768 * 768;
    ushort_t* Wv1_t  = us + uo;  uo += (size_t)4096 * 768;
    ushort_t* Wout_t = us + uo;  uo += (size_t)768 * 768;
    ushort_t* outp_b = us + uo;  uo += (size_t)M * 768;

    // 1. all conversions
    const int nb_x = (M * 768 / 4) / 256;
    const int nb_c = (Mn * 768 / 4) / 256;
    prep<<<nb_x + nb_c + 576 * 3 + 3072, 256, 0, stream>>>(
        x, context, Wq, Wk, Wv1, Wout, x_b, ctx_b, Wq_t, Wk_t, Wv1_t, Wout_t, b, n);

    // 2. q, k, h1 GEMMs fused (global_load_lds staging)
    const int tq = (M / 128) * 6, tk = (Mn / 128) * 6, th = (Mn / 128) * 32;
    gemm3<<<tq + tk + th, 256, 0, stream>>>(x_b, ctx_b, Wq_t, Wk_t, Wv1_t,
                                            qb, kb, h1b, b, n);

    // 3. LN row stats + scores fused
    stats_scores<<<Mn + b * 8 * (n / 128), 256, 0, stream>>>(
        h1b, qb, kb, muh, rstdh, S, b, n);

    // 4. chunked attention-V with online-softmax partials (128-chunks)
    attn_pv<<<dim3(nsp, M), 256, 0, stream>>>(S, muh, rstdh, h1b, Apart, n, nsp);

    // 5. merge + LN affine + Wc
    merge_wc<<<M, 256, 0, stream>>>(Apart, ln_g, ln_b, Wc, outp_b, nsp);

    // 6. out = outp @ Wout
    gemm_out<<<dim3(6, M / 128), 256, 0, stream>>>(outp_b, Wout_t, out, M, 768, 768);
}